// Round 10
// baseline (385.760 us; speedup 1.0000x reference)
//
#include <hip/hip_runtime.h>
#include <hip/hip_cooperative_groups.h>
#include <hip/hip_bf16.h>
#include <math.h>

namespace cg = cooperative_groups;

#define B_   16
#define N_   32
#define I_   1152
#define DIN  16
#define D_   64
#define IPC  144           // i's per block (CU)
#define IPW  72            // i's per wave (2 i-halves x 4 d-tiles = 8 waves)

#if __has_builtin(__builtin_amdgcn_exp2f)
#define EXP2(x) __builtin_amdgcn_exp2f(x)
#else
#define EXP2(x) exp2f(x)
#endif

#define LOG2E 1.4426950408889634f

typedef __attribute__((ext_vector_type(8))) short short8v;
typedef __attribute__((ext_vector_type(4))) float f32x4;
typedef __attribute__((ext_vector_type(4))) unsigned int u32x4;

__device__ __forceinline__ float squash1(float s) {
    float sq = s * s;
    return (sq / (1.0f + sq)) * s * rsqrtf(sq + 1e-9f);
}
__device__ __forceinline__ unsigned int bfh(float v) {
    return (unsigned int)__builtin_bit_cast(unsigned short, __float2bfloat16(v));
}
__device__ __forceinline__ float bff(unsigned int hi16) {
    return __builtin_bit_cast(float, hi16 << 16);
}

// Persistent cooperative kernel: one block per CU, block (n, ic) owns
// x_hat[n][ic*144..+144][*][*] in REGISTERS (packed bf16, 144 VGPRs/lane).
// W is streamed from HBM exactly once (151 MB total). Routing reductions:
// in-reg pass -> LDS wave-pair combine -> small global partial -> grid.sync
// -> every block re-reduces the 8 ic-partials for its n (redundant, cheap,
// deterministic). 3 grid barriers total. No x_hat store/reload (R9 spent
// ~230 MB of HBM on that).
// MFMA: C[16d x 16b] = A[16d x 32k] * B[32k x 16b], K 0..15 = W_hi bf16,
// K 16..31 = W_lo residual, inputs duplicated -> fp32-grade W precision.
// A lane l: row=l&15, koct=(l>>4)&1, lanes>=32 supply W_lo.
// C lane l: col b=l&15, row d = mt*16 + (l>>4)*4 + r.
__global__ __launch_bounds__(512, 2) void k_caps(const float* __restrict__ inp,
                                                 const float* __restrict__ W,
                                                 float* __restrict__ outp,
                                                 float* __restrict__ p0,
                                                 float* __restrict__ za1,
                                                 float* __restrict__ za2) {
    __shared__ __align__(16) unsigned short xs[IPC * 256];  // [il][ko][b][8] bf16 (72KB)
    __shared__ __align__(16) float red[8 * 64 * 8];         // [w][l][8] combine (16KB)

    cg::grid_group grid = cg::this_grid();

    const int bid = blockIdx.x;
    const int n  = bid >> 3;
    const int ic = bid & 7;
    const int t  = threadIdx.x;
    const int l  = t & 63;
    const int w  = t >> 6;                 // wave 0..7
    const int mt = w & 3;                  // d m-tile
    const int ih = w >> 2;                 // i-half (0/1)
    const int b  = l & 15;
    const int dg = l >> 4;                 // 0..3
    const int ko = dg & 1;
    const bool loHalf = (l >= 32);
    const int d0 = mt * 16 + dg * 4;

    // ---- stage inputs -> bf16 LDS tile [il][ko][b][8]
    for (int rep = 0; rep < 5; ++rep) {
        int pair = rep * 512 + t;
        if (pair < IPC * 16) {
            int il = pair >> 4, bb = pair & 15;
            const float* src = inp + (size_t)bb * (I_ * DIN) + (size_t)(ic * IPC + il) * DIN;
            f32x4 a0 = *(const f32x4*)src;
            f32x4 a1 = *(const f32x4*)(src + 4);
            f32x4 a2 = *(const f32x4*)(src + 8);
            f32x4 a3 = *(const f32x4*)(src + 12);
            u32x4 q0, q1;
            q0.x = (bfh(a0.y) << 16) | bfh(a0.x);
            q0.y = (bfh(a0.w) << 16) | bfh(a0.z);
            q0.z = (bfh(a1.y) << 16) | bfh(a1.x);
            q0.w = (bfh(a1.w) << 16) | bfh(a1.z);
            q1.x = (bfh(a2.y) << 16) | bfh(a2.x);
            q1.y = (bfh(a2.w) << 16) | bfh(a2.z);
            q1.z = (bfh(a3.y) << 16) | bfh(a3.x);
            q1.w = (bfh(a3.w) << 16) | bfh(a3.z);
            *(u32x4*)(xs + il * 256 + bb * 8)       = q0;   // k 0..7
            *(u32x4*)(xs + il * 256 + 128 + bb * 8) = q1;   // k 8..15
        }
    }
    __syncthreads();

    // ---- phase 1: MFMA over this wave's 72 i's; pack x_hat into regs
    const float* wb = W + ((size_t)(n * I_ + ic * IPC + ih * IPW) * 64 + mt * 16 + b) * 16 + ko * 8;

    unsigned int pk[IPW * 2];
    f32x4 s0v = {0.f, 0.f, 0.f, 0.f};

    #pragma unroll
    for (int c = 0; c < IPW / 4; ++c) {
        f32x4 wv[8];
        #pragma unroll
        for (int j = 0; j < 4; ++j) {
            const f32x4* p = (const f32x4*)(wb + (size_t)(c * 4 + j) * 1024);
            wv[2 * j] = p[0]; wv[2 * j + 1] = p[1];
        }
        #pragma unroll
        for (int j = 0; j < 4; ++j) {
            const int il = ih * IPW + c * 4 + j;
            short8v bfrag = *(const short8v*)(xs + il * 256 + ko * 128 + b * 8);
            short8v afrag;
            #pragma unroll
            for (int q = 0; q < 8; ++q) {
                float wq = wv[2 * j + (q >> 2)][q & 3];
                unsigned int hi = bfh(wq);
                unsigned int lo = bfh(wq - bff(hi));
                afrag[q] = (short)(loHalf ? lo : hi);
            }
            f32x4 acc = __builtin_amdgcn_mfma_f32_16x16x32_bf16(
                afrag, bfrag, (f32x4){0.f, 0.f, 0.f, 0.f}, 0, 0, 0);
            s0v += acc;
            pk[(c * 4 + j) * 2]     = (bfh(acc[1]) << 16) | bfh(acc[0]);
            pk[(c * 4 + j) * 2 + 1] = (bfh(acc[3]) << 16) | bfh(acc[2]);
        }
    }

    // s0 wave-pair combine -> p0[n][ic][b*64+d]
    *(f32x4*)(red + (w * 64 + l) * 8) = s0v;
    __syncthreads();
    if (ih == 0) {
        f32x4 o = *(const f32x4*)(red + ((w ^ 4) * 64 + l) * 8);
        f32x4 s = s0v + o;
        *(f32x4*)(p0 + (size_t)(n * 8 + ic) * 1024 + b * 64 + d0) = s;
    }
    __threadfence();
    grid.sync();

#define ROUTE_PASS(C2, ZZ, AA)                                                  \
    _Pragma("unroll")                                                           \
    for (int iw = 0; iw < IPW; ++iw) {                                          \
        unsigned int u0 = pk[iw * 2], u1 = pk[iw * 2 + 1];                      \
        float x0 = __builtin_bit_cast(float, u0 << 16);                         \
        float x1 = __builtin_bit_cast(float, u0 & 0xffff0000u);                 \
        float x2 = __builtin_bit_cast(float, u1 << 16);                         \
        float x3 = __builtin_bit_cast(float, u1 & 0xffff0000u);                 \
        float e0 = EXP2(x0 * C2[0]); ZZ[0] += e0; AA[0] = fmaf(e0, x0, AA[0]);  \
        float e1 = EXP2(x1 * C2[1]); ZZ[1] += e1; AA[1] = fmaf(e1, x1, AA[1]);  \
        float e2 = EXP2(x2 * C2[2]); ZZ[2] += e2; AA[2] = fmaf(e2, x2, AA[2]);  \
        float e3 = EXP2(x3 * C2[3]); ZZ[3] += e3; AA[3] = fmaf(e3, x3, AA[3]);  \
    }

    // ---- phase 2: coef0 = squash(mean); routing pass 1
    float coef0[4], c2[4];
    {
        f32x4 s = {0.f, 0.f, 0.f, 0.f};
        #pragma unroll
        for (int j = 0; j < 8; ++j)
            s += *(const f32x4*)(p0 + (size_t)(n * 8 + j) * 1024 + b * 64 + d0);
        #pragma unroll
        for (int r = 0; r < 4; ++r) {
            coef0[r] = squash1(s[r] * (1.0f / (float)I_));
            c2[r] = coef0[r] * LOG2E;
        }
    }
    float z[4] = {0, 0, 0, 0}, a[4] = {0, 0, 0, 0};
    ROUTE_PASS(c2, z, a)

    *(f32x4*)(red + (w * 64 + l) * 8)     = (f32x4){z[0], z[1], z[2], z[3]};
    *(f32x4*)(red + (w * 64 + l) * 8 + 4) = (f32x4){a[0], a[1], a[2], a[3]};
    __syncthreads();
    if (ih == 0) {
        const float* pr = red + ((w ^ 4) * 64 + l) * 8;
        size_t base = ((size_t)(n * 8 + ic) * 1024 + b * 64 + d0) * 2;
        *(f32x4*)(za1 + base)     = (f32x4){z[0] + pr[0], a[0] + pr[4], z[1] + pr[1], a[1] + pr[5]};
        *(f32x4*)(za1 + base + 4) = (f32x4){z[2] + pr[2], a[2] + pr[6], z[3] + pr[3], a[3] + pr[7]};
    }
    __threadfence();
    grid.sync();

    // ---- phase 3: coef1 = coef0 + squash(a/z); routing pass 2
    float cn2[4];
    {
        f32x4 Z = {0.f, 0.f, 0.f, 0.f}, A = {0.f, 0.f, 0.f, 0.f};
        #pragma unroll
        for (int j = 0; j < 8; ++j) {
            size_t base = ((size_t)(n * 8 + j) * 1024 + b * 64 + d0) * 2;
            f32x4 v0 = *(const f32x4*)(za1 + base);
            f32x4 v1 = *(const f32x4*)(za1 + base + 4);
            Z += (f32x4){v0[0], v0[2], v1[0], v1[2]};
            A += (f32x4){v0[1], v0[3], v1[1], v1[3]};
        }
        #pragma unroll
        for (int r = 0; r < 4; ++r)
            cn2[r] = (coef0[r] + squash1(A[r] / Z[r])) * LOG2E;
    }
    float z2[4] = {0, 0, 0, 0}, a2[4] = {0, 0, 0, 0};
    ROUTE_PASS(cn2, z2, a2)

    __syncthreads();
    *(f32x4*)(red + (w * 64 + l) * 8)     = (f32x4){z2[0], z2[1], z2[2], z2[3]};
    *(f32x4*)(red + (w * 64 + l) * 8 + 4) = (f32x4){a2[0], a2[1], a2[2], a2[3]};
    __syncthreads();
    if (ih == 0) {
        const float* pr = red + ((w ^ 4) * 64 + l) * 8;
        size_t base = ((size_t)(n * 8 + ic) * 1024 + b * 64 + d0) * 2;
        *(f32x4*)(za2 + base)     = (f32x4){z2[0] + pr[0], a2[0] + pr[4], z2[1] + pr[1], a2[1] + pr[5]};
        *(f32x4*)(za2 + base + 4) = (f32x4){z2[2] + pr[2], a2[2] + pr[6], z2[3] + pr[3], a2[3] + pr[7]};
    }
    __threadfence();
    grid.sync();

    // ---- phase 4: final squash + output (ic==0 blocks write; out[b][n][d])
    if (ic == 0 && ih == 0) {
        f32x4 Z = {0.f, 0.f, 0.f, 0.f}, A = {0.f, 0.f, 0.f, 0.f};
        #pragma unroll
        for (int j = 0; j < 8; ++j) {
            size_t base = ((size_t)(n * 8 + j) * 1024 + b * 64 + d0) * 2;
            f32x4 v0 = *(const f32x4*)(za2 + base);
            f32x4 v1 = *(const f32x4*)(za2 + base + 4);
            Z += (f32x4){v0[0], v0[2], v1[0], v1[2]};
            A += (f32x4){v0[1], v0[3], v1[1], v1[3]};
        }
        f32x4 o;
        #pragma unroll
        for (int r = 0; r < 4; ++r) o[r] = squash1(A[r] / Z[r]);
        *(f32x4*)(outp + (size_t)b * (N_ * D_) + n * 64 + d0) = o;
    }
#undef ROUTE_PASS
}

extern "C" void kernel_launch(void* const* d_in, const int* in_sizes, int n_in,
                              void* d_out, int out_size, void* d_ws, size_t ws_size,
                              hipStream_t stream) {
    const float* inp = (const float*)d_in[0];
    const float* W   = (const float*)d_in[1];
    float* out = (float*)d_out;

    float* p0  = (float*)d_ws;                          // 32*8*1024 f32   = 1 MB
    float* za1 = (float*)((char*)d_ws + (1u << 20));    // 32*8*1024*2 f32 = 2 MB
    float* za2 = (float*)((char*)d_ws + (3u << 20));    // 2 MB

    void* args[] = {(void*)&inp, (void*)&W, (void*)&out, (void*)&p0, (void*)&za1, (void*)&za2};
    hipLaunchCooperativeKernel((void*)k_caps, dim3(256), dim3(512), args, 0, stream);
}

// Round 11
// 76.633 us; speedup vs baseline: 5.0339x; 5.0339x over previous
//
#include <hip/hip_runtime.h>
#include <hip/hip_bf16.h>
#include <math.h>

#define B_   16
#define N_   32
#define I_   1152
#define DIN  16
#define D_   64
#define TI   16            // i's per k_xhat block
#define IB   (I_/TI)       // 72 i-tiles
#define IC   16            // i-chunks in routing (72 i each)
#define BND  (B_*N_*D_)    // 32768

#if __has_builtin(__builtin_amdgcn_exp2f)
#define EXP2(x) __builtin_amdgcn_exp2f(x)
#else
#define EXP2(x) exp2f(x)
#endif

#define LOG2E 1.4426950408889634f

typedef __attribute__((ext_vector_type(8))) short short8v;
typedef __attribute__((ext_vector_type(4))) float f32x4;
typedef __attribute__((ext_vector_type(4))) unsigned int u32x4;
typedef __attribute__((ext_vector_type(2))) unsigned int u32x2;

__device__ __forceinline__ float squash1(float s) {
    float sq = s * s;
    return (sq / (1.0f + sq)) * s * rsqrtf(sq + 1e-9f);
}
__device__ __forceinline__ unsigned int bfh(float v) {
    return (unsigned int)__builtin_bit_cast(unsigned short, __float2bfloat16(v));
}
__device__ __forceinline__ float bff(unsigned int hi16) {
    return __builtin_bit_cast(float, hi16 << 16);
}

// K1: x_hat via MFMA. R9 engine + TI=16 with a 2-deep REGISTER-PIPELINED W
// stream: fully-unrolled loop {issue 8 dwordx4 for group c+1; compute group
// c}, no stores interleaved (pk in regs, stores at end). Keeps >=8 W loads
// in flight through the whole compute phase (R9's burst-then-idle pattern
// left the VMEM queue empty ~2/3 of each wave's life => ~2 TB/s W stream).
// hi/lo W-residual trick: K-slots 0..15 = W_hi, 16..31 = W_lo, inputs
// duplicated -> fp32-grade W precision per mfma_f32_16x16x32_bf16.
// C-frag: col b=l&15, d = mt*16+(l>>4)*4+r. xh2 tile: element off = mt*256+4l
// (lane-order => wave writes 512B contiguous per i).
__global__ __launch_bounds__(256, 3) void k_xhat(const float* __restrict__ inp,
                                                 const float* __restrict__ W,
                                                 unsigned short* __restrict__ xh2,
                                                 float* __restrict__ part) {
    __shared__ __align__(16) unsigned short xs[4096];   // [b][il][ko][8] bf16, swizzled (8KB)
    const int bx = blockIdx.x;
    const int n  = bx / IB;
    const int ib = bx % IB;
    const int i0 = ib * TI;
    const int t  = threadIdx.x;
    const int l  = t & 63;
    const int mt = t >> 6;                 // wave id = d m-tile (0..3)
    const int row = l & 15;
    const int ko  = (l >> 4) & 1;          // k-octet for A/B frags
    const bool loHalf = (l >= 32);

    // ---- stage inputs -> bf16 LDS tile [b][il][ko][8], XOR-swizzled
    #pragma unroll
    for (int rep = 0; rep < 2; ++rep) {
        int s   = rep * 256 + t;           // 512 slots = 16b x 16il x 2ko
        int bb  = s >> 5;
        int il  = (s >> 1) & 15;
        int sko = s & 1;
        const float* src = inp + (size_t)bb * (I_ * DIN) + (size_t)(i0 + il) * DIN + sko * 8;
        f32x4 a0 = *(const f32x4*)src;
        f32x4 a1 = *(const f32x4*)(src + 4);
        u32x4 p;
        p.x = (bfh(a0.y) << 16) | bfh(a0.x);
        p.y = (bfh(a0.w) << 16) | bfh(a0.z);
        p.z = (bfh(a1.y) << 16) | bfh(a1.x);
        p.w = (bfh(a1.w) << 16) | bfh(a1.z);
        int base = (bb * 512 + il * 32 + sko * 16) ^ ((bb & 7) << 4);
        *(u32x4*)((char*)xs + base) = p;
    }
    __syncthreads();

    const float* wb = W + ((size_t)(n * I_ + i0) * 64 + mt * 16 + row) * 16 + ko * 8;

    unsigned int pk[TI * 2];
    f32x4 s0v = {0.f, 0.f, 0.f, 0.f};

#define LOADG(DST, C) {                                                        \
        _Pragma("unroll")                                                      \
        for (int j = 0; j < 4; ++j) {                                          \
            const f32x4* p = (const f32x4*)(wb + (size_t)((C) * 4 + j) * 1024);\
            DST[2 * j] = p[0]; DST[2 * j + 1] = p[1];                          \
        } }

#define COMPG(SRC, C) {                                                        \
        _Pragma("unroll")                                                      \
        for (int j = 0; j < 4; ++j) {                                          \
            const int i = (C) * 4 + j;                                         \
            int xaddr = ((l & 15) * 512 + i * 32 + ko * 16) ^ (((l & 15) & 7) << 4); \
            short8v bfrag = *(const short8v*)((const char*)xs + xaddr);        \
            short8v afrag;                                                     \
            _Pragma("unroll")                                                  \
            for (int q = 0; q < 8; ++q) {                                      \
                float wq = SRC[2 * j + (q >> 2)][q & 3];                       \
                unsigned int hi = bfh(wq);                                     \
                unsigned int lo = bfh(wq - bff(hi));                           \
                afrag[q] = (short)(loHalf ? lo : hi);                          \
            }                                                                  \
            f32x4 acc = __builtin_amdgcn_mfma_f32_16x16x32_bf16(               \
                afrag, bfrag, (f32x4){0.f, 0.f, 0.f, 0.f}, 0, 0, 0);           \
            s0v += acc;                                                        \
            pk[i * 2]     = (bfh(acc[1]) << 16) | bfh(acc[0]);                 \
            pk[i * 2 + 1] = (bfh(acc[3]) << 16) | bfh(acc[2]);                 \
        } }

    f32x4 wA[8], wB[8];
    LOADG(wA, 0)
    LOADG(wB, 1)
    COMPG(wA, 0)
    LOADG(wA, 2)
    COMPG(wB, 1)
    LOADG(wB, 3)
    COMPG(wA, 2)
    COMPG(wB, 3)
#undef LOADG
#undef COMPG

    // ---- s0 partials (register-only), then fully-coalesced xh stores
    size_t pidx = (((size_t)ib * B_ + (l & 15)) * N_ + n) * 64 + mt * 16 + (l >> 4) * 4;
    *(f32x4*)(part + pidx) = s0v;

    #pragma unroll
    for (int i = 0; i < TI; ++i) {
        u32x2 v;
        v.x = pk[i * 2];
        v.y = pk[i * 2 + 1];
        size_t off = (size_t)(n * I_ + i0 + i) * 1024 + (size_t)t * 4;  // mt*256 + 4*l
        *reinterpret_cast<u32x2*>(xh2 + off) = v;
    }
}

// K2: coef = squash(mean over i of x_hat) — routing iteration 0.
// part layout [ib][b][n][d]; t packs (b,n,d) = coef index.
__global__ __launch_bounds__(256) void k_out0(const float* __restrict__ part,
                                              float* __restrict__ coef) {
    const int t = blockIdx.x * 256 + threadIdx.x;
    float s = 0.0f;
    for (int j = 0; j < IB; ++j) s += part[(size_t)j * BND + t];
    s *= (1.0f / (float)I_);
    coef[t] = squash1(s);
}

// K3: routing partial pass. xh2 tile is lane-ordered: thread t owns element
// offset 4t per i-tile => wave reads 512B CONTIGUOUS per i. Thread coords:
// b = t&15, d0 = (t>>4)*4. |logit|<=~50 -> exp2 safe without max-tracking.
// part2 layout [ic][n][b][d][2] = {z,a}.
__global__ __launch_bounds__(256) void k_rpart(const unsigned short* __restrict__ xh2,
                                               const float* __restrict__ coef,
                                               float* __restrict__ part2) {
    const int bx = blockIdx.x;
    const int n  = bx >> 4;
    const int ic = bx & 15;
    const int t  = threadIdx.x;
    const int b  = t & 15;
    const int d0 = (t >> 4) * 4;

    const unsigned short* base = xh2 + ((size_t)n * I_ + (size_t)ic * (I_ / IC)) * 1024
                               + (size_t)t * 4;
    f32x4 c4 = *(const f32x4*)(coef + ((size_t)b * N_ + n) * 64 + d0);
    float c2[4] = {c4.x * LOG2E, c4.y * LOG2E, c4.z * LOG2E, c4.w * LOG2E};
    float z[4] = {0, 0, 0, 0}, a[4] = {0, 0, 0, 0};

    #pragma unroll 8
    for (int i = 0; i < I_ / IC; ++i) {
        u32x2 u = *(const u32x2*)(base + (size_t)i * 1024);
        unsigned short s4[4] = {(unsigned short)(u.x & 0xffffu), (unsigned short)(u.x >> 16),
                                (unsigned short)(u.y & 0xffffu), (unsigned short)(u.y >> 16)};
        #pragma unroll
        for (int j = 0; j < 4; ++j) {
            float x = bff(s4[j]);
            float e = EXP2(x * c2[j]);
            z[j] += e;
            a[j] = fmaf(e, x, a[j]);
        }
    }

    size_t pidx = ((((size_t)ic * N_ + n) * 16 + b) * 64 + d0) * 2;
    f32x4 v0 = {z[0], a[0], z[1], a[1]};
    f32x4 v1 = {z[2], a[2], z[3], a[3]};
    *(f32x4*)(part2 + pidx)     = v0;
    *(f32x4*)(part2 + pidx + 4) = v1;
}

// K4: routing finisher. gid packs (n,b,d) matching part2 inner order.
// final=0: coef += squash(a/z). final=1: out[b][n][d] = squash(a/z).
__global__ __launch_bounds__(256) void k_rfin(const float* __restrict__ part2,
                                              const float* __restrict__ coefIn,
                                              float* __restrict__ outp,
                                              int final_) {
    const int gid = blockIdx.x * 256 + threadIdx.x;     // n*1024 + b*64 + d
    float Z = 0.0f, A = 0.0f;
    #pragma unroll
    for (int ic = 0; ic < IC; ++ic) {
        const float* p = part2 + ((size_t)ic * BND + gid) * 2;
        Z += p[0];
        A += p[1];
    }
    const int d = gid & 63, b = (gid >> 6) & 15, n = gid >> 10;
    const int ci = (b * N_ + n) * D_ + d;
    float o = squash1(A / Z);
    outp[ci] = final_ ? o : (coefIn[ci] + o);
}

extern "C" void kernel_launch(void* const* d_in, const int* in_sizes, int n_in,
                              void* d_out, int out_size, void* d_ws, size_t ws_size,
                              hipStream_t stream) {
    const float* inp = (const float*)d_in[0];
    const float* W   = (const float*)d_in[1];
    float* out = (float*)d_out;

    unsigned short* xh2 = (unsigned short*)d_ws;                    // 75,497,472 B
    float* part  = (float*)((char*)d_ws + 75497472);                //  9,437,184 B
    float* part2 = (float*)((char*)d_ws + 84934656);                //  4,194,304 B
    float* coef  = (float*)((char*)d_ws + 89128960);                //    131,072 B

    k_xhat<<<dim3(N_ * IB), dim3(256), 0, stream>>>(inp, W, xh2, part);
    k_out0<<<dim3(BND / 256), dim3(256), 0, stream>>>(part, coef);
    k_rpart<<<dim3(N_ * IC), dim3(256), 0, stream>>>(xh2, coef, part2);
    k_rfin <<<dim3(BND / 256), dim3(256), 0, stream>>>(part2, coef, coef, 0);
    k_rpart<<<dim3(N_ * IC), dim3(256), 0, stream>>>(xh2, coef, part2);
    k_rfin <<<dim3(BND / 256), dim3(256), 0, stream>>>(part2, coef, out, 1);
}